// Round 15
// baseline (172.397 us; speedup 1.0000x reference)
//
#include <hip/hip_runtime.h>
#include <hip/hip_bf16.h>
#include <math.h>

#define NHEAD 16
#define HD 64
#define TSEQ 2048
#define CEMB 1024

typedef __attribute__((ext_vector_type(8))) short short8;
typedef __attribute__((ext_vector_type(4))) float f32x4;
typedef __attribute__((ext_vector_type(16))) float f32x16;

__device__ inline unsigned short f2bf(float f) {
  union { float f; unsigned u; } x; x.f = f;
  unsigned r = x.u + 0x7FFFu + ((x.u >> 16) & 1u);
  return (unsigned short)(r >> 16);
}

__device__ inline unsigned pk2(float a, float b) {
  __hip_bfloat162 t = __float22bfloat162_rn(make_float2(a, b));  // low=a, high=b
  union { __hip_bfloat162 v; unsigned u; } c; c.v = t;
  return c.u;
}

// raw 2^x (v_exp_f32), no libm wrapper, no extra mul
__device__ inline float ex2(float x) {
#if __has_builtin(__builtin_amdgcn_exp2f)
  return __builtin_amdgcn_exp2f(x);
#else
  float r; asm("v_exp_f32 %0, %1" : "=v"(r) : "v"(x)); return r;
#endif
}

__device__ inline void gload16(const void* g, void* l) {
  __builtin_amdgcn_global_load_lds(
      (const __attribute__((address_space(1))) unsigned int*)g,
      (__attribute__((address_space(3))) unsigned int*)l, 16, 0, 0);
}

// ---------- cast x fp32 -> bf16 ----------
__global__ __launch_bounds__(256) void castx(const float* __restrict__ in,
                                             unsigned short* __restrict__ out) {
  int i = blockIdx.x * 256 + threadIdx.x;
  float4 v = ((const float4*)in)[i];
  ushort4 o;
  o.x = f2bf(v.x); o.y = f2bf(v.y); o.z = f2bf(v.z); o.w = f2bf(v.w);
  ((ushort4*)out)[i] = o;
}

// ---------- transpose W [1024][N] fp32 -> Wt [N][1024] bf16 ----------
__global__ __launch_bounds__(256) void transW(const float* __restrict__ W,
                                              unsigned short* __restrict__ Wt,
                                              int N) {
  __shared__ float t[64][65];
  const int tid = threadIdx.x;
  const int rb = blockIdx.y * 64;
  const int cb = blockIdx.x * 64;
#pragma unroll
  for (int i = 0; i < 16; ++i) {
    int idx = i * 256 + tid, r = idx >> 6, cl = idx & 63;
    t[r][cl] = W[(size_t)(rb + r) * N + cb + cl];
  }
  __syncthreads();
#pragma unroll
  for (int i = 0; i < 16; ++i) {
    int idx = i * 256 + tid, r = idx >> 6, cl = idx & 63;
    Wt[(size_t)(cb + r) * 1024 + rb + cl] = f2bf(t[cl][r]);
  }
}

// ---------- MFMA GEMM BMx128, BK=64, global_load_lds + XOR swizzle ----------
// V^T TILED LAYOUT (this round): V workspace is [bh][tt=t/32][d][ti=t%32] so
// lif_sw's per-KV-tile V reads (read ~32x more often than written) become
// contiguous-4KB-window accesses instead of 4KB-scattered 32B segments.
// Store-side coalescing unchanged (256B segments either way). MODE 1 BM=64
// (R14, -6 us). XCD swizzle (T1) kept. V-epilogue LDS restage (R11, -8.4 us).
template <int MODE>
__global__ __launch_bounds__(256) void mm128(const unsigned short* __restrict__ A,
                                             const unsigned short* __restrict__ Bt,
                                             const float* __restrict__ bias,
                                             void* __restrict__ out0,
                                             unsigned short* __restrict__ ko,
                                             unsigned short* __restrict__ vto) {
  constexpr int BM = (MODE == 0) ? 128 : 64;   // tile rows
  constexpr int MFR = BM / 32;                 // m-frags per wave
  __shared__ __align__(16) unsigned char smem[BM * 128 + 16384];
  unsigned char* Asm = smem;                   // BM x 128B
  unsigned char* Bsm = smem + BM * 128;        // 128 x 128B
  const int tid = threadIdx.x;
  const int lane = tid & 63;
  const int w = tid >> 6;
  const int wm = w >> 1, wn = w & 1;
  const int c = lane & 15, g = lane >> 4;

  // XCD-aware chunked swizzle of the flat workgroup id (bijective: nwg%8==0)
  const int nwgx = (MODE == 0) ? 24 : 8;
  const int nwgy = (MODE == 0) ? 32 : 64;
  const int nwg = nwgx * nwgy;
  int fid = blockIdx.x + nwgx * blockIdx.y;
  fid = (fid & 7) * (nwg >> 3) + (fid >> 3);
  const int rowbase = (fid / nwgx) * BM;
  const int colbase = (fid % nwgx) * 128;

  f32x4 acc[MFR][4];
#pragma unroll
  for (int m = 0; m < MFR; ++m)
#pragma unroll
    for (int n = 0; n < 4; ++n) acc[m][n] = (f32x4){0.f, 0.f, 0.f, 0.f};

  const unsigned char* Ab = (const unsigned char*)(A + (size_t)rowbase * 1024);
  const unsigned char* Bb = (const unsigned char*)(Bt + (size_t)colbase * 1024);
  const int swz = (c & 7) << 4;

  for (int kt = 0; kt < 16; ++kt) {
    __syncthreads();
#pragma unroll
    for (int it = 0; it < 4; ++it) {
      const int L = it * 4096 + tid * 16;
      const int row = L >> 7;
      const int sc = (L & 127) ^ ((row & 7) << 4);
      if (it < BM / 32)
        gload16(Ab + (size_t)row * 2048 + kt * 128 + sc, Asm + L);
      gload16(Bb + (size_t)row * 2048 + kt * 128 + sc, Bsm + L);
    }
    __syncthreads();
#pragma unroll
    for (int ks = 0; ks < 2; ++ks) {
      const int cb = ks * 64 + 16 * g;
      short8 af[MFR], bf[4];
#pragma unroll
      for (int m = 0; m < MFR; ++m)
        af[m] = *(const short8*)(Asm + (wm * (BM / 2) + m * 16 + c) * 128 + (cb ^ swz));
#pragma unroll
      for (int n = 0; n < 4; ++n)
        bf[n] = *(const short8*)(Bsm + (wn * 64 + n * 16 + c) * 128 + (cb ^ swz));
#pragma unroll
      for (int m = 0; m < MFR; ++m)
#pragma unroll
        for (int n = 0; n < 4; ++n)
          acc[m][n] = __builtin_amdgcn_mfma_f32_16x16x32_bf16(af[m], bf[n], acc[m][n], 0, 0, 0);
    }
  }

  const bool vblock = (MODE == 0) && (colbase >= 2048);
  if (vblock) __syncthreads();  // all LDS reads done before smem reuse as vbuf

#pragma unroll
  for (int m = 0; m < MFR; ++m) {
    const int rw = rowbase + wm * (BM / 2) + m * 16 + 4 * g;
#pragma unroll
    for (int n = 0; n < 4; ++n) {
      const int col = colbase + wn * 64 + n * 16 + c;
      const float bz = bias[col];
      if (MODE == 0) {
        unsigned short* qo = (unsigned short*)out0;
        const int sel = col >> 10, cc = col & 1023, hh = cc >> 6, d = cc & 63;
#pragma unroll
        for (int r = 0; r < 4; ++r) {
          const int row = rw + r;
          const int b = row >> 11, t = row & 2047;
          const float val = acc[m][n][r] + bz;
          const size_t bh = (size_t)(b * NHEAD + hh);
          if (sel == 0)
            // 0.125 * log2(e): scores arrive in log2 domain for raw v_exp_f32
            qo[(bh * TSEQ + t) * HD + d] = f2bf(val * 0.18033688011112042f);
          else if (sel == 1)
            ko[(bh * TSEQ + t) * HD + d] = f2bf(val);
          else {
            // stage into vbuf (swizzled) for coalesced V^T write below
            const int col_l = wn * 64 + n * 16 + c;
            const int row_l = (rw & 127) + r;
            const int rowx = row_l ^ ((col_l & 15) << 3);
            ((unsigned short*)smem)[col_l * 128 + rowx] = f2bf(val);
          }
        }
      } else {
        float* out = (float*)out0;
#pragma unroll
        for (int r = 0; r < 4; ++r)
          out[(size_t)(rw + r) * 1024 + col] = acc[m][n][r] + bz;
      }
    }
  }

  if (vblock) {
    __syncthreads();
    const int b = rowbase >> 11;
    const int t0base = rowbase & 2047;
    const int ln = tid & 15;
#pragma unroll
    for (int it = 0; it < 8; ++it) {
      const int cl = it * 16 + (tid >> 4);            // local col = v-dim slot
      const int vcol = colbase - 2048 + cl;
      const int hh = vcol >> 6, d = vcol & 63;
      const size_t bh = (size_t)(b * NHEAD + hh);
      const int rowx = (ln * 8) ^ ((cl & 15) << 3);   // 8-aligned chunk swizzle
      short8 v = *(const short8*)((const unsigned short*)smem + cl * 128 + rowx);
      // tiled V^T: [bh][tt][d][ti], tt = t/32, ti = t%32 (t = t0base + ln*8)
      const int tt = (t0base >> 5) + (ln >> 2);
      const int ti = (ln & 3) * 8;
      *(short8*)(vto + ((size_t)((bh * 64 + tt) * 64 + d)) * 32 + ti) = v;
    }
  }
}

// ---------- LIF attention, swapped-operand 32x32 in-register softmax ----------
// THIS ROUND (two address-only changes; compute/sync structure untouched):
//  1) XCD-chunked block swizzle: groups 4 consecutive bh (32 blocks each) per
//     XCD so each XCD L2 caches only its 4 bh's K/V/Q (~3 MB, fits 4 MB L2)
//     instead of thrashing on all 32 bh (24 MB). K/V reads become L2 hits.
//  2) V^T tiled layout [bh][tt][d][ti]: per-tile V reads are now contiguous
//     4KB windows (64B-strided) instead of 32B segments scattered 4KB apart.
// setprio remains forbidden here (R12 miscompile).
__global__ __launch_bounds__(256) void lif_sw(
    const unsigned short* __restrict__ qb,   // [BH][T][64] bf16, pre-scaled 0.125*log2e
    const unsigned short* __restrict__ kb,   // [BH][T][64] bf16
    const unsigned short* __restrict__ vtb,  // [BH][64][64][32] bf16 tiled V^T
    const float* __restrict__ thr_p, const float* __restrict__ leak_p,
    const float* __restrict__ steep_p,
    unsigned short* __restrict__ y) {        // [B][T][1024] bf16
  __shared__ float obuf[8][32][33];          // [s*2+db][q][dl] 33.8 KB
  __shared__ float lbufA[4][32];
  __shared__ float lbufB[4][32];
  __shared__ float msbuf[4][32];

  // XCD-chunked swizzle: hw dispatches flat ids round-robin across XCDs;
  // remap so chunk c (= 4 consecutive bh, 128 blocks) has flat%8 == c.
  const int flat = blockIdx.x + 32 * blockIdx.y;
  const int logical = (flat & 7) * 128 + (flat >> 3);
  const int bh = logical >> 5;
  const int byy = logical & 31;

  const int h = bh & (NHEAD - 1);
  const int b = bh >> 4;
  const int tid = threadIdx.x;
  const int s = tid >> 6;                    // kv split 0..3 (strided)
  const int lane = tid & 63;
  const int qv = lane & 31;                  // query col
  const int hi = lane >> 5;
  const int klb = 4 * hi;

  const int qtA = 63 - byy;                  // big tile
  const int qtB = byy;                       // small tile
  const int ntA = qtA + 1, ntB = qtB + 1;

  const unsigned short* qp = qb + (size_t)bh * TSEQ * HD;
  const unsigned short* kp = kb + (size_t)bh * TSEQ * HD;
  const unsigned short* vp = vtb + (size_t)bh * HD * TSEQ;

  const float thr = fabsf(thr_p[h]) * 0.1f;
  const float lk = 1.f / (1.f + __expf(-leak_p[h]));
  const float st = log1pf(__expf(steep_p[h]));
  const float stc = st * 1.44269504088896f;  // st * log2(e)
  const float stthr2 = stc * thr;
  const float omlk = 1.f - lk;

  // per-lane bases (bh-dependent only)
  const unsigned short* kpl  = kp + (size_t)qv * HD + 8 * hi;        // + t*2048
  // tiled V^T: element (d, t) at ((tt*64)+d)*32 + ti; per-tile stride 2048
  const unsigned short* vpl0 = vp + qv * 32 + 8 * hi;                // d = qv
  const unsigned short* vpl1 = vp + (32 + qv) * 32 + 8 * hi;         // d = 32+qv

  // Q^T B-frags for BOTH q-tiles
  const unsigned short* qplA = qp + (size_t)(qtA * 32 + qv) * HD + 8 * hi;
  const short8 qfA0 = *(const short8*)(qplA);
  const short8 qfA1 = *(const short8*)(qplA + 16);
  const short8 qfA2 = *(const short8*)(qplA + 32);
  const short8 qfA3 = *(const short8*)(qplA + 48);
  const unsigned short* qplB = qp + (size_t)(qtB * 32 + qv) * HD + 8 * hi;
  const short8 qfB0 = *(const short8*)(qplB);
  const short8 qfB1 = *(const short8*)(qplB + 16);
  const short8 qfB2 = *(const short8*)(qplB + 32);
  const short8 qfB3 = *(const short8*)(qplB + 48);

  // ---- fused pass A: one K load, two independent QK/exp streams ----
  // strided split: wave s owns tiles t = s, s+4, ... -> B-work balanced
  float lA = 0.f, lB = 0.f;
  for (int t = s; t < ntA; t += 4) {
    const unsigned short* kt = kpl + (size_t)t * (32 * HD);
    const short8 k0 = *(const short8*)(kt);
    const short8 k1 = *(const short8*)(kt + 16);
    const short8 k2 = *(const short8*)(kt + 32);
    const short8 k3 = *(const short8*)(kt + 48);
    const bool doB = (t < ntB);
    f32x16 sa = {};
    sa = __builtin_amdgcn_mfma_f32_32x32x16_bf16(k0, qfA0, sa, 0, 0, 0);
    sa = __builtin_amdgcn_mfma_f32_32x32x16_bf16(k1, qfA1, sa, 0, 0, 0);
    sa = __builtin_amdgcn_mfma_f32_32x32x16_bf16(k2, qfA2, sa, 0, 0, 0);
    sa = __builtin_amdgcn_mfma_f32_32x32x16_bf16(k3, qfA3, sa, 0, 0, 0);
    f32x16 sb = {};
    if (doB) {  // issue B-chain BEFORE A's exps: covers sa chain latency
      sb = __builtin_amdgcn_mfma_f32_32x32x16_bf16(k0, qfB0, sb, 0, 0, 0);
      sb = __builtin_amdgcn_mfma_f32_32x32x16_bf16(k1, qfB1, sb, 0, 0, 0);
      sb = __builtin_amdgcn_mfma_f32_32x32x16_bf16(k2, qfB2, sb, 0, 0, 0);
      sb = __builtin_amdgcn_mfma_f32_32x32x16_bf16(k3, qfB3, sb, 0, 0, 0);
    }
    if (t == qtA) {
#pragma unroll
      for (int j = 0; j < 16; ++j)
        if ((j & 3) + 8 * (j >> 2) + klb > qv) sa[j] = -1e30f;
    }
#pragma unroll
    for (int j = 0; j < 16; ++j) lA += ex2(sa[j]);
    if (doB) {
      if (t == qtB) {
#pragma unroll
        for (int j = 0; j < 16; ++j)
          if ((j & 3) + 8 * (j >> 2) + klb > qv) sb[j] = -1e30f;
      }
#pragma unroll
      for (int j = 0; j < 16; ++j) lB += ex2(sb[j]);
    }
  }
  lA += __shfl_xor(lA, 32, 64);
  lB += __shfl_xor(lB, 32, 64);
  if (hi == 0) { lbufA[s][qv] = lA; lbufB[s][qv] = lB; }
  __syncthreads();
  const float stli2A =
      stc / ((lbufA[0][qv] + lbufA[1][qv]) + (lbufA[2][qv] + lbufA[3][qv]));
  const float stli2B =
      stc / ((lbufB[0][qv] + lbufB[1][qv]) + (lbufB[2][qv] + lbufB[3][qv]));

  // ---- pass B (LIF + PV, unnormalized m = e*w; li cancels in y = O/ms) ----
  f32x16 o0, o1;
  float ms;
  auto passB = [&](int nt, int qt, float stli2, const short8& q0,
                   const short8& q1, const short8& q2, const short8& q3) {
    o0 = (f32x16){}; o1 = (f32x16){};
    ms = 0.f;
    for (int t = s; t < nt; t += 4) {   // strided split
      const unsigned short* kt = kpl + (size_t)t * (32 * HD);
      f32x16 sv = {};
      sv = __builtin_amdgcn_mfma_f32_32x32x16_bf16(*(const short8*)(kt), q0, sv, 0, 0, 0);
      sv = __builtin_amdgcn_mfma_f32_32x32x16_bf16(*(const short8*)(kt + 16), q1, sv, 0, 0, 0);
      sv = __builtin_amdgcn_mfma_f32_32x32x16_bf16(*(const short8*)(kt + 32), q2, sv, 0, 0, 0);
      sv = __builtin_amdgcn_mfma_f32_32x32x16_bf16(*(const short8*)(kt + 48), q3, sv, 0, 0, 0);
      const unsigned short* v0 = vpl0 + t * 2048;   // tiled: 2048 per tt
      const unsigned short* v1 = vpl1 + t * 2048;
      short8 va00 = *(const short8*)(v0);
      short8 va01 = *(const short8*)(v0 + 16);
      short8 va10 = *(const short8*)(v1);
      short8 va11 = *(const short8*)(v1 + 16);

      if (t == qt) {
#pragma unroll
        for (int j = 0; j < 16; ++j)
          if ((j & 3) + 8 * (j >> 2) + klb > qv) sv[j] = -1e30f;
      }
      unsigned cw[8];
#pragma unroll
      for (int jj = 0; jj < 8; ++jj) {
        float e0 = ex2(sv[2 * jj]);
        float e1 = ex2(sv[2 * jj + 1]);
        float u0 = ex2(fmaf(-stli2, e0, stthr2));
        float u1 = ex2(fmaf(-stli2, e1, stthr2));
        float f0 = __builtin_amdgcn_rcpf(1.f + u0);
        float f1 = __builtin_amdgcn_rcpf(1.f + u1);
        float m0 = e0 * fmaf(omlk, f0, lk);
        float m1 = e1 * fmaf(omlk, f1, lk);
        ms += m0;
        ms += m1;
        cw[jj] = pk2(m0, m1);
      }
      asm("v_permlane32_swap_b32 %0, %1" : "+v"(cw[0]), "+v"(cw[2]));
      asm("v_permlane32_swap_b32 %0, %1" : "+v"(cw[1]), "+v"(cw[3]));
      asm("v_permlane32_swap_b32 %0, %1" : "+v"(cw[4]), "+v"(cw[6]));
      asm("v_permlane32_swap_b32 %0, %1" : "+v"(cw[5]), "+v"(cw[7]));
      union { unsigned u[4]; short8 v; } B0, B1;
      B0.u[0] = cw[0]; B0.u[1] = cw[1]; B0.u[2] = cw[2]; B0.u[3] = cw[3];
      B1.u[0] = cw[4]; B1.u[1] = cw[5]; B1.u[2] = cw[6]; B1.u[3] = cw[7];
      o0 = __builtin_amdgcn_mfma_f32_32x32x16_bf16(va00, B0.v, o0, 0, 0, 0);
      o0 = __builtin_amdgcn_mfma_f32_32x32x16_bf16(va01, B1.v, o0, 0, 0, 0);
      o1 = __builtin_amdgcn_mfma_f32_32x32x16_bf16(va10, B0.v, o1, 0, 0, 0);
      o1 = __builtin_amdgcn_mfma_f32_32x32x16_bf16(va11, B1.v, o1, 0, 0, 0);
    }
  };

  // ---- single-round split combine + store (2 barriers) ----
  auto writeout = [&](int qbase) {
    ms += __shfl_xor(ms, 32, 64);
    if (hi == 0) msbuf[s][qv] = ms;
#pragma unroll
    for (int j = 0; j < 16; ++j) {
      const int dl = (j & 3) + 8 * (j >> 2) + klb;
      obuf[s * 2 + 0][qv][dl] = o0[j];
      obuf[s * 2 + 1][qv][dl] = o1[j];
    }
    __syncthreads();
    {
      const int d = tid & 63;
      const int db = d >> 5, dl = d & 31;
#pragma unroll
      for (int it = 0; it < 8; ++it) {
        const int q = (tid >> 6) * 8 + it;
        const float acc = ((obuf[0 + db][q][dl] + obuf[2 + db][q][dl]) +
                           (obuf[4 + db][q][dl] + obuf[6 + db][q][dl]));
        const float mt = (msbuf[0][q] + msbuf[1][q]) + (msbuf[2][q] + msbuf[3][q]);
        y[((size_t)(b * TSEQ) + qbase + q) * CEMB + h * HD + d] =
            f2bf(acc / (mt + 1e-8f));
      }
    }
    __syncthreads();  // guard obuf/msbuf reuse by the next phase
  };

  // pass B + writeout for the big tile A, then the small tile B
  passB(ntA, qtA, stli2A, qfA0, qfA1, qfA2, qfA3);
  writeout(qtA * 32);
  passB(ntB, qtB, stli2B, qfB0, qfB1, qfB2, qfB3);
  writeout(qtB * 32);
}

extern "C" void kernel_launch(void* const* d_in, const int* in_sizes, int n_in,
                              void* d_out, int out_size, void* d_ws, size_t ws_size,
                              hipStream_t stream) {
  const float* x      = (const float*)d_in[0];
  const float* W_attn = (const float*)d_in[1];
  const float* b_attn = (const float*)d_in[2];
  const float* W_proj = (const float*)d_in[3];
  const float* b_proj = (const float*)d_in[4];
  const float* thr    = (const float*)d_in[5];
  const float* leak   = (const float*)d_in[6];
  const float* steep  = (const float*)d_in[7];
  float* out = (float*)d_out;

  unsigned short* xb   = (unsigned short*)d_ws;              // 4096x1024
  unsigned short* Wat  = xb + (size_t)4096 * 1024;           // 3072x1024
  unsigned short* Wpt  = Wat + (size_t)3072 * 1024;          // 1024x1024
  unsigned short* qws  = Wpt + (size_t)1024 * 1024;          // [32][2048][64]
  unsigned short* kws  = qws + (size_t)32 * 2048 * 64;
  unsigned short* vtws = kws + (size_t)32 * 2048 * 64;       // [32][64][64][32]
  unsigned short* yb   = vtws + (size_t)32 * 2048 * 64;      // 4096x1024
  // total ~48 MB of d_ws

  castx<<<4096, 256, 0, stream>>>(x, xb);
  transW<<<dim3(48, 16), 256, 0, stream>>>(W_attn, Wat, 3072);
  transW<<<dim3(16, 16), 256, 0, stream>>>(W_proj, Wpt, 1024);
  mm128<0><<<dim3(24, 32), 256, 0, stream>>>(xb, Wat, b_attn, qws, kws, vtws);
  lif_sw<<<dim3(32, 32), 256, 0, stream>>>(qws, kws, vtws, thr, leak, steep, yb);
  mm128<1><<<dim3(8, 64), 256, 0, stream>>>(yb, Wpt, b_proj, out, nullptr, nullptr);
}

// Round 16
// 170.488 us; speedup vs baseline: 1.0112x; 1.0112x over previous
//
#include <hip/hip_runtime.h>
#include <hip/hip_bf16.h>
#include <math.h>

#define NHEAD 16
#define HD 64
#define TSEQ 2048
#define CEMB 1024

typedef __attribute__((ext_vector_type(8))) short short8;
typedef __attribute__((ext_vector_type(4))) float f32x4;
typedef __attribute__((ext_vector_type(16))) float f32x16;

__device__ inline unsigned short f2bf(float f) {
  union { float f; unsigned u; } x; x.f = f;
  unsigned r = x.u + 0x7FFFu + ((x.u >> 16) & 1u);
  return (unsigned short)(r >> 16);
}

__device__ inline unsigned pk2(float a, float b) {
  __hip_bfloat162 t = __float22bfloat162_rn(make_float2(a, b));  // low=a, high=b
  union { __hip_bfloat162 v; unsigned u; } c; c.v = t;
  return c.u;
}

// raw 2^x (v_exp_f32), no libm wrapper, no extra mul
__device__ inline float ex2(float x) {
#if __has_builtin(__builtin_amdgcn_exp2f)
  return __builtin_amdgcn_exp2f(x);
#else
  float r; asm("v_exp_f32 %0, %1" : "=v"(r) : "v"(x)); return r;
#endif
}

__device__ inline void gload16(const void* g, void* l) {
  __builtin_amdgcn_global_load_lds(
      (const __attribute__((address_space(1))) unsigned int*)g,
      (__attribute__((address_space(3))) unsigned int*)l, 16, 0, 0);
}

// ---------- cast x fp32 -> bf16 ----------
__global__ __launch_bounds__(256) void castx(const float* __restrict__ in,
                                             unsigned short* __restrict__ out) {
  int i = blockIdx.x * 256 + threadIdx.x;
  float4 v = ((const float4*)in)[i];
  ushort4 o;
  o.x = f2bf(v.x); o.y = f2bf(v.y); o.z = f2bf(v.z); o.w = f2bf(v.w);
  ((ushort4*)out)[i] = o;
}

// ---------- transpose W [1024][N] fp32 -> Wt [N][1024] bf16 ----------
__global__ __launch_bounds__(256) void transW(const float* __restrict__ W,
                                              unsigned short* __restrict__ Wt,
                                              int N) {
  __shared__ float t[64][65];
  const int tid = threadIdx.x;
  const int rb = blockIdx.y * 64;
  const int cb = blockIdx.x * 64;
#pragma unroll
  for (int i = 0; i < 16; ++i) {
    int idx = i * 256 + tid, r = idx >> 6, cl = idx & 63;
    t[r][cl] = W[(size_t)(rb + r) * N + cb + cl];
  }
  __syncthreads();
#pragma unroll
  for (int i = 0; i < 16; ++i) {
    int idx = i * 256 + tid, r = idx >> 6, cl = idx & 63;
    Wt[(size_t)(cb + r) * 1024 + rb + cl] = f2bf(t[cl][r]);
  }
}

// ---------- MFMA GEMM BMx128, BK=64, global_load_lds + XOR swizzle ----------
// Q/K EPILOGUE RESTAGE (this round): Q/K outputs were 64 scalar 2B stores per
// thread (4x32B scattered segments per instr) — same pathology class as the
// V-scatter R11 fixed (-8.4 us). Now ALL MODE-0 outputs stage through LDS:
//   V: col-major [col][128] + XOR swizzle (R11, unchanged)
//   Q/K: row-major [128][136] (padded; 2-way-free writes, conflict-free 16B
//        reads) -> 8 dwordx4 stores/thread into contiguous [t][d] runs.
// Values bit-identical (same f2bf, different route). MODE 1 BM=64 (R14).
template <int MODE>
__global__ __launch_bounds__(256) void mm128(const unsigned short* __restrict__ A,
                                             const unsigned short* __restrict__ Bt,
                                             const float* __restrict__ bias,
                                             void* __restrict__ out0,
                                             unsigned short* __restrict__ ko,
                                             unsigned short* __restrict__ vto) {
  constexpr int BM = (MODE == 0) ? 128 : 64;   // tile rows
  constexpr int MFR = BM / 32;                 // m-frags per wave
  constexpr int SMEMSZ = (MODE == 0) ? 36864 : (BM * 128 + 16384);
  __shared__ __align__(16) unsigned char smem[SMEMSZ];
  unsigned char* Asm = smem;                   // BM x 128B
  unsigned char* Bsm = smem + BM * 128;        // 128 x 128B
  const int tid = threadIdx.x;
  const int lane = tid & 63;
  const int w = tid >> 6;
  const int wm = w >> 1, wn = w & 1;
  const int c = lane & 15, g = lane >> 4;

  // XCD-aware chunked swizzle of the flat workgroup id (bijective: nwg%8==0)
  const int nwgx = (MODE == 0) ? 24 : 8;
  const int nwgy = (MODE == 0) ? 32 : 64;
  const int nwg = nwgx * nwgy;
  int fid = blockIdx.x + nwgx * blockIdx.y;
  fid = (fid & 7) * (nwg >> 3) + (fid >> 3);
  const int rowbase = (fid / nwgx) * BM;
  const int colbase = (fid % nwgx) * 128;

  f32x4 acc[MFR][4];
#pragma unroll
  for (int m = 0; m < MFR; ++m)
#pragma unroll
    for (int n = 0; n < 4; ++n) acc[m][n] = (f32x4){0.f, 0.f, 0.f, 0.f};

  const unsigned char* Ab = (const unsigned char*)(A + (size_t)rowbase * 1024);
  const unsigned char* Bb = (const unsigned char*)(Bt + (size_t)colbase * 1024);
  const int swz = (c & 7) << 4;

  for (int kt = 0; kt < 16; ++kt) {
    __syncthreads();
#pragma unroll
    for (int it = 0; it < 4; ++it) {
      const int L = it * 4096 + tid * 16;
      const int row = L >> 7;
      const int sc = (L & 127) ^ ((row & 7) << 4);
      if (it < BM / 32)
        gload16(Ab + (size_t)row * 2048 + kt * 128 + sc, Asm + L);
      gload16(Bb + (size_t)row * 2048 + kt * 128 + sc, Bsm + L);
    }
    __syncthreads();
#pragma unroll
    for (int ks = 0; ks < 2; ++ks) {
      const int cb = ks * 64 + 16 * g;
      short8 af[MFR], bf[4];
#pragma unroll
      for (int m = 0; m < MFR; ++m)
        af[m] = *(const short8*)(Asm + (wm * (BM / 2) + m * 16 + c) * 128 + (cb ^ swz));
#pragma unroll
      for (int n = 0; n < 4; ++n)
        bf[n] = *(const short8*)(Bsm + (wn * 64 + n * 16 + c) * 128 + (cb ^ swz));
#pragma unroll
      for (int m = 0; m < MFR; ++m)
#pragma unroll
        for (int n = 0; n < 4; ++n)
          acc[m][n] = __builtin_amdgcn_mfma_f32_16x16x32_bf16(af[m], bf[n], acc[m][n], 0, 0, 0);
    }
  }

  const int sel = (MODE == 0) ? (colbase >> 10) : -1;  // 0=Q,1=K,2=V
  if (MODE == 0) __syncthreads();  // all LDS reads done before smem reuse

#pragma unroll
  for (int m = 0; m < MFR; ++m) {
    const int rw = rowbase + wm * (BM / 2) + m * 16 + 4 * g;
#pragma unroll
    for (int n = 0; n < 4; ++n) {
      const int col = colbase + wn * 64 + n * 16 + c;
      const float bz = bias[col];
      if (MODE == 0) {
        const int col_l = wn * 64 + n * 16 + c;
#pragma unroll
        for (int r = 0; r < 4; ++r) {
          const int row_l = ((rw + r) & 127);
          float val = acc[m][n][r] + bz;
          if (sel == 0)
            // 0.125 * log2(e): scores arrive in log2 domain for raw v_exp_f32
            val *= 0.18033688011112042f;
          if (sel == 2) {
            // col-major + XOR swizzle for coalesced V^T write below (R11)
            const int rowx = row_l ^ ((col_l & 15) << 3);
            ((unsigned short*)smem)[col_l * 128 + rowx] = f2bf(val);
          } else {
            // row-major padded for coalesced Q/K write below
            ((unsigned short*)smem)[row_l * 136 + col_l] = f2bf(val);
          }
        }
      } else {
        float* out = (float*)out0;
#pragma unroll
        for (int r = 0; r < 4; ++r)
          out[(size_t)(rw + r) * 1024 + col] = acc[m][n][r] + bz;
      }
    }
  }

  if (MODE == 0) {
    __syncthreads();
    const int b = rowbase >> 11;
    const int t0base = rowbase & 2047;
    if (sel == 2) {
      const int ln = tid & 15;
#pragma unroll
      for (int it = 0; it < 8; ++it) {
        const int cl = it * 16 + (tid >> 4);          // local col = v-dim slot
        const int vcol = colbase - 2048 + cl;
        const int hh = vcol >> 6, d = vcol & 63;
        const size_t bh = (size_t)(b * NHEAD + hh);
        const int rowx = (ln * 8) ^ ((cl & 15) << 3); // 8-aligned chunk swizzle
        short8 v = *(const short8*)((const unsigned short*)smem + cl * 128 + rowx);
        *(short8*)(vto + (bh * HD + d) * TSEQ + t0base + ln * 8) = v;
      }
    } else {
      unsigned short* dst = (sel == 0) ? (unsigned short*)out0 : ko;
      const int hh0 = (colbase & 1023) >> 6;
      const int d0 = (tid & 7) * 8;
#pragma unroll
      for (int it = 0; it < 8; ++it) {
        const int pair = it * 32 + (tid >> 3);        // 0..255
        const int row_l = pair >> 1;
        const int hh = hh0 + (pair & 1);
        const size_t bh = (size_t)(b * NHEAD + hh);
        short8 v = *(const short8*)((const unsigned short*)smem +
                                    row_l * 136 + (pair & 1) * 64 + d0);
        *(short8*)(dst + (bh * TSEQ + t0base + row_l) * HD + d0) = v;
      }
    }
  }
}

// ---------- LIF attention, swapped-operand 32x32 in-register softmax ----------
// EXACT R14 version (passing, lif_sw ~105 us; R15's memory-side changes were
// null and are reverted). setprio forbidden here (R12 miscompile).
__global__ __launch_bounds__(256) void lif_sw(
    const unsigned short* __restrict__ qb,   // [BH][T][64] bf16, pre-scaled 0.125*log2e
    const unsigned short* __restrict__ kb,   // [BH][T][64] bf16
    const unsigned short* __restrict__ vtb,  // [BH][64][T] bf16
    const float* __restrict__ thr_p, const float* __restrict__ leak_p,
    const float* __restrict__ steep_p,
    unsigned short* __restrict__ y) {        // [B][T][1024] bf16
  __shared__ float obuf[8][32][33];          // [s*2+db][q][dl] 33.8 KB
  __shared__ float lbufA[4][32];
  __shared__ float lbufB[4][32];
  __shared__ float msbuf[4][32];

  const int bh = blockIdx.x;
  const int h = bh & (NHEAD - 1);
  const int b = bh >> 4;
  const int tid = threadIdx.x;
  const int s = tid >> 6;                    // kv split 0..3 (strided)
  const int lane = tid & 63;
  const int qv = lane & 31;                  // query col
  const int hi = lane >> 5;
  const int klb = 4 * hi;

  const int qtA = 63 - blockIdx.y;           // big tile
  const int qtB = blockIdx.y;                // small tile
  const int ntA = qtA + 1, ntB = qtB + 1;

  const unsigned short* qp = qb + (size_t)bh * TSEQ * HD;
  const unsigned short* kp = kb + (size_t)bh * TSEQ * HD;
  const unsigned short* vp = vtb + (size_t)bh * HD * TSEQ;

  const float thr = fabsf(thr_p[h]) * 0.1f;
  const float lk = 1.f / (1.f + __expf(-leak_p[h]));
  const float st = log1pf(__expf(steep_p[h]));
  const float stc = st * 1.44269504088896f;  // st * log2(e)
  const float stthr2 = stc * thr;
  const float omlk = 1.f - lk;

  // per-lane bases (bh-dependent only)
  const unsigned short* kpl  = kp + (size_t)qv * HD + 8 * hi;        // + t*2048
  const unsigned short* vpl0 = vp + (size_t)qv * TSEQ + 8 * hi;      // + t*32
  const unsigned short* vpl1 = vp + (size_t)(32 + qv) * TSEQ + 8 * hi;

  // Q^T B-frags for BOTH q-tiles
  const unsigned short* qplA = qp + (size_t)(qtA * 32 + qv) * HD + 8 * hi;
  const short8 qfA0 = *(const short8*)(qplA);
  const short8 qfA1 = *(const short8*)(qplA + 16);
  const short8 qfA2 = *(const short8*)(qplA + 32);
  const short8 qfA3 = *(const short8*)(qplA + 48);
  const unsigned short* qplB = qp + (size_t)(qtB * 32 + qv) * HD + 8 * hi;
  const short8 qfB0 = *(const short8*)(qplB);
  const short8 qfB1 = *(const short8*)(qplB + 16);
  const short8 qfB2 = *(const short8*)(qplB + 32);
  const short8 qfB3 = *(const short8*)(qplB + 48);

  // ---- fused pass A: one K load, two independent QK/exp streams ----
  // strided split: wave s owns tiles t = s, s+4, ... -> B-work balanced
  float lA = 0.f, lB = 0.f;
  for (int t = s; t < ntA; t += 4) {
    const unsigned short* kt = kpl + (size_t)t * (32 * HD);
    const short8 k0 = *(const short8*)(kt);
    const short8 k1 = *(const short8*)(kt + 16);
    const short8 k2 = *(const short8*)(kt + 32);
    const short8 k3 = *(const short8*)(kt + 48);
    const bool doB = (t < ntB);
    f32x16 sa = {};
    sa = __builtin_amdgcn_mfma_f32_32x32x16_bf16(k0, qfA0, sa, 0, 0, 0);
    sa = __builtin_amdgcn_mfma_f32_32x32x16_bf16(k1, qfA1, sa, 0, 0, 0);
    sa = __builtin_amdgcn_mfma_f32_32x32x16_bf16(k2, qfA2, sa, 0, 0, 0);
    sa = __builtin_amdgcn_mfma_f32_32x32x16_bf16(k3, qfA3, sa, 0, 0, 0);
    f32x16 sb = {};
    if (doB) {  // issue B-chain BEFORE A's exps: covers sa chain latency
      sb = __builtin_amdgcn_mfma_f32_32x32x16_bf16(k0, qfB0, sb, 0, 0, 0);
      sb = __builtin_amdgcn_mfma_f32_32x32x16_bf16(k1, qfB1, sb, 0, 0, 0);
      sb = __builtin_amdgcn_mfma_f32_32x32x16_bf16(k2, qfB2, sb, 0, 0, 0);
      sb = __builtin_amdgcn_mfma_f32_32x32x16_bf16(k3, qfB3, sb, 0, 0, 0);
    }
    if (t == qtA) {
#pragma unroll
      for (int j = 0; j < 16; ++j)
        if ((j & 3) + 8 * (j >> 2) + klb > qv) sa[j] = -1e30f;
    }
#pragma unroll
    for (int j = 0; j < 16; ++j) lA += ex2(sa[j]);
    if (doB) {
      if (t == qtB) {
#pragma unroll
        for (int j = 0; j < 16; ++j)
          if ((j & 3) + 8 * (j >> 2) + klb > qv) sb[j] = -1e30f;
      }
#pragma unroll
      for (int j = 0; j < 16; ++j) lB += ex2(sb[j]);
    }
  }
  lA += __shfl_xor(lA, 32, 64);
  lB += __shfl_xor(lB, 32, 64);
  if (hi == 0) { lbufA[s][qv] = lA; lbufB[s][qv] = lB; }
  __syncthreads();
  const float stli2A =
      stc / ((lbufA[0][qv] + lbufA[1][qv]) + (lbufA[2][qv] + lbufA[3][qv]));
  const float stli2B =
      stc / ((lbufB[0][qv] + lbufB[1][qv]) + (lbufB[2][qv] + lbufB[3][qv]));

  // ---- pass B (LIF + PV, unnormalized m = e*w; li cancels in y = O/ms) ----
  f32x16 o0, o1;
  float ms;
  auto passB = [&](int nt, int qt, float stli2, const short8& q0,
                   const short8& q1, const short8& q2, const short8& q3) {
    o0 = (f32x16){}; o1 = (f32x16){};
    ms = 0.f;
    for (int t = s; t < nt; t += 4) {   // strided split
      const unsigned short* kt = kpl + (size_t)t * (32 * HD);
      f32x16 sv = {};
      sv = __builtin_amdgcn_mfma_f32_32x32x16_bf16(*(const short8*)(kt), q0, sv, 0, 0, 0);
      sv = __builtin_amdgcn_mfma_f32_32x32x16_bf16(*(const short8*)(kt + 16), q1, sv, 0, 0, 0);
      sv = __builtin_amdgcn_mfma_f32_32x32x16_bf16(*(const short8*)(kt + 32), q2, sv, 0, 0, 0);
      sv = __builtin_amdgcn_mfma_f32_32x32x16_bf16(*(const short8*)(kt + 48), q3, sv, 0, 0, 0);
      const unsigned short* v0 = vpl0 + t * 32;
      const unsigned short* v1 = vpl1 + t * 32;
      short8 va00 = *(const short8*)(v0);
      short8 va01 = *(const short8*)(v0 + 16);
      short8 va10 = *(const short8*)(v1);
      short8 va11 = *(const short8*)(v1 + 16);

      if (t == qt) {
#pragma unroll
        for (int j = 0; j < 16; ++j)
          if ((j & 3) + 8 * (j >> 2) + klb > qv) sv[j] = -1e30f;
      }
      unsigned cw[8];
#pragma unroll
      for (int jj = 0; jj < 8; ++jj) {
        float e0 = ex2(sv[2 * jj]);
        float e1 = ex2(sv[2 * jj + 1]);
        float u0 = ex2(fmaf(-stli2, e0, stthr2));
        float u1 = ex2(fmaf(-stli2, e1, stthr2));
        float f0 = __builtin_amdgcn_rcpf(1.f + u0);
        float f1 = __builtin_amdgcn_rcpf(1.f + u1);
        float m0 = e0 * fmaf(omlk, f0, lk);
        float m1 = e1 * fmaf(omlk, f1, lk);
        ms += m0;
        ms += m1;
        cw[jj] = pk2(m0, m1);
      }
      asm("v_permlane32_swap_b32 %0, %1" : "+v"(cw[0]), "+v"(cw[2]));
      asm("v_permlane32_swap_b32 %0, %1" : "+v"(cw[1]), "+v"(cw[3]));
      asm("v_permlane32_swap_b32 %0, %1" : "+v"(cw[4]), "+v"(cw[6]));
      asm("v_permlane32_swap_b32 %0, %1" : "+v"(cw[5]), "+v"(cw[7]));
      union { unsigned u[4]; short8 v; } B0, B1;
      B0.u[0] = cw[0]; B0.u[1] = cw[1]; B0.u[2] = cw[2]; B0.u[3] = cw[3];
      B1.u[0] = cw[4]; B1.u[1] = cw[5]; B1.u[2] = cw[6]; B1.u[3] = cw[7];
      o0 = __builtin_amdgcn_mfma_f32_32x32x16_bf16(va00, B0.v, o0, 0, 0, 0);
      o0 = __builtin_amdgcn_mfma_f32_32x32x16_bf16(va01, B1.v, o0, 0, 0, 0);
      o1 = __builtin_amdgcn_mfma_f32_32x32x16_bf16(va10, B0.v, o1, 0, 0, 0);
      o1 = __builtin_amdgcn_mfma_f32_32x32x16_bf16(va11, B1.v, o1, 0, 0, 0);
    }
  };

  // ---- single-round split combine + store (2 barriers) ----
  auto writeout = [&](int qbase) {
    ms += __shfl_xor(ms, 32, 64);
    if (hi == 0) msbuf[s][qv] = ms;
#pragma unroll
    for (int j = 0; j < 16; ++j) {
      const int dl = (j & 3) + 8 * (j >> 2) + klb;
      obuf[s * 2 + 0][qv][dl] = o0[j];
      obuf[s * 2 + 1][qv][dl] = o1[j];
    }
    __syncthreads();
    {
      const int d = tid & 63;
      const int db = d >> 5, dl = d & 31;
#pragma unroll
      for (int it = 0; it < 8; ++it) {
        const int q = (tid >> 6) * 8 + it;
        const float acc = ((obuf[0 + db][q][dl] + obuf[2 + db][q][dl]) +
                           (obuf[4 + db][q][dl] + obuf[6 + db][q][dl]));
        const float mt = (msbuf[0][q] + msbuf[1][q]) + (msbuf[2][q] + msbuf[3][q]);
        y[((size_t)(b * TSEQ) + qbase + q) * CEMB + h * HD + d] =
            f2bf(acc / (mt + 1e-8f));
      }
    }
    __syncthreads();  // guard obuf/msbuf reuse by the next phase
  };

  // pass B + writeout for the big tile A, then the small tile B
  passB(ntA, qtA, stli2A, qfA0, qfA1, qfA2, qfA3);
  writeout(qtA * 32);
  passB(ntB, qtB, stli2B, qfB0, qfB1, qfB2, qfB3);
  writeout(qtB * 32);
}

extern "C" void kernel_launch(void* const* d_in, const int* in_sizes, int n_in,
                              void* d_out, int out_size, void* d_ws, size_t ws_size,
                              hipStream_t stream) {
  const float* x      = (const float*)d_in[0];
  const float* W_attn = (const float*)d_in[1];
  const float* b_attn = (const float*)d_in[2];
  const float* W_proj = (const float*)d_in[3];
  const float* b_proj = (const float*)d_in[4];
  const float* thr    = (const float*)d_in[5];
  const float* leak   = (const float*)d_in[6];
  const float* steep  = (const float*)d_in[7];
  float* out = (float*)d_out;

  unsigned short* xb   = (unsigned short*)d_ws;              // 4096x1024
  unsigned short* Wat  = xb + (size_t)4096 * 1024;           // 3072x1024
  unsigned short* Wpt  = Wat + (size_t)3072 * 1024;          // 1024x1024
  unsigned short* qws  = Wpt + (size_t)1024 * 1024;          // [32][2048][64]
  unsigned short* kws  = qws + (size_t)32 * 2048 * 64;
  unsigned short* vtws = kws + (size_t)32 * 2048 * 64;       // [32][64][2048]
  unsigned short* yb   = vtws + (size_t)32 * 2048 * 64;      // 4096x1024
  // total ~48 MB of d_ws

  castx<<<4096, 256, 0, stream>>>(x, xb);
  transW<<<dim3(48, 16), 256, 0, stream>>>(W_attn, Wat, 3072);
  transW<<<dim3(16, 16), 256, 0, stream>>>(W_proj, Wpt, 1024);
  mm128<0><<<dim3(24, 32), 256, 0, stream>>>(xb, Wat, b_attn, qws, kws, vtws);
  lif_sw<<<dim3(32, 32), 256, 0, stream>>>(qws, kws, vtws, thr, leak, steep, yb);
  mm128<1><<<dim3(8, 64), 256, 0, stream>>>(yb, Wpt, b_proj, out, nullptr, nullptr);
}